// Round 15
// baseline (451.790 us; speedup 1.0000x reference)
//
#include <hip/hip_runtime.h>

#define N_NODES 50000
#define N_EDGES 600000
#define N_GRAPHS 2048
#define EMB 128
#define TDIM 384
#define TS_LD 392               // padded LDS row stride (shorts): 2-way bank alias only
#define HN (N_NODES * EMB)
#define SCAN_NB ((N_NODES + 255) / 256)   // 196

typedef __attribute__((ext_vector_type(8))) short bf16x8;
typedef __attribute__((ext_vector_type(4))) float f32x4;
#define MFMA_BF16(a, b, c) __builtin_amdgcn_mfma_f32_16x16x32_bf16(a, b, c, 0, 0, 0)

__device__ inline unsigned short f2bf(float f) {
  unsigned int u = __float_as_uint(f);
  u += 0x7fffu + ((u >> 16) & 1u);   // round to nearest even
  return (unsigned short)(u >> 16);
}
__device__ inline float bf2f(unsigned short b) {
  return __uint_as_float(((unsigned int)b) << 16);
}

// nt load of an edge record {src, packed_attr} via long long (int2 class type
// is rejected by __builtin_nontemporal_load)
__device__ inline int2 nt_se(const int2* p) {
  long long v = __builtin_nontemporal_load((const long long*)p);
  return int2{(int)(unsigned int)(v & 0xffffffffll), (int)(v >> 32)};
}

// ---------------- Atom encoder: h (fp32, nt) + h_bf (bf16 gather source, cached) ----------------
__global__ __launch_bounds__(128) void k_atom(const int* __restrict__ x,
                                              const float* __restrict__ atom_emb,
                                              float* __restrict__ h,
                                              unsigned short* __restrict__ h_bf) {
  int n = blockIdx.x, e = threadIdx.x;
  const int* xr = x + n * 9;
  float acc = 0.f;
#pragma unroll
  for (int c = 0; c < 9; ++c) acc += atom_emb[(c * 100 + xr[c]) * EMB + e];
  __builtin_nontemporal_store(acc, &h[n * EMB + e]);   // streamed: read once by layer-0 epilogue
  h_bf[n * EMB + e] = f2bf(acc);                        // hot: gathered all of layer 0
}

// ---------------- CSR build ----------------
__global__ __launch_bounds__(256) void k_hist(const int* __restrict__ ei, int* __restrict__ deg) {
  int e = blockIdx.x * 256 + threadIdx.x;
  if (e < N_EDGES) atomicAdd(&deg[ei[N_EDGES + e]], 1);
}

__global__ __launch_bounds__(256) void k_scan_a(const int* __restrict__ deg,
                                                int* __restrict__ row_start,
                                                int* __restrict__ partials) {
  __shared__ int s[256];
  const int tid = threadIdx.x;
  const int i = blockIdx.x * 256 + tid;
  int v = (i < N_NODES) ? deg[i] : 0;
  s[tid] = v;
  __syncthreads();
  for (int off = 1; off < 256; off <<= 1) {
    int t = (tid >= off) ? s[tid - off] : 0;
    __syncthreads();
    s[tid] += t;
    __syncthreads();
  }
  if (i < N_NODES) row_start[i] = s[tid] - v;
  if (tid == 255) partials[blockIdx.x] = s[255];
}

__global__ __launch_bounds__(256) void k_scan_b(int* __restrict__ partials,
                                                int* __restrict__ row_start) {
  __shared__ int s[256];
  const int tid = threadIdx.x;
  int v = (tid < SCAN_NB) ? partials[tid] : 0;
  s[tid] = v;
  __syncthreads();
  for (int off = 1; off < 256; off <<= 1) {
    int t = (tid >= off) ? s[tid - off] : 0;
    __syncthreads();
    s[tid] += t;
    __syncthreads();
  }
  if (tid < SCAN_NB) partials[tid] = s[tid] - v;
  if (tid == 255) row_start[N_NODES] = s[255];
}

__global__ __launch_bounds__(256) void k_scan_c(int* __restrict__ row_start,
                                                const int* __restrict__ partials,
                                                int* __restrict__ cursor) {
  const int i = blockIdx.x * 256 + threadIdx.x;
  if (i < N_NODES) {
    int r = row_start[i] + partials[blockIdx.x];
    row_start[i] = r;
    cursor[i] = r;
  }
}

// Scatter edges into CSR order: one int2{src, packed_attr} per edge.
__global__ __launch_bounds__(256) void k_scatter(const int* __restrict__ ei,
                                                 const int* __restrict__ ea,
                                                 int* __restrict__ cursor,
                                                 int2* __restrict__ sorted_se) {
  int e = blockIdx.x * 256 + threadIdx.x;
  if (e >= N_EDGES) return;
  int src = __builtin_nontemporal_load(&ei[e]);
  int dst = __builtin_nontemporal_load(&ei[N_EDGES + e]);
  int a0 = __builtin_nontemporal_load(&ea[e * 3 + 0]);
  int a1 = __builtin_nontemporal_load(&ea[e * 3 + 1]);
  int a2 = __builtin_nontemporal_load(&ea[e * 3 + 2]);
  int pos = atomicAdd(&cursor[dst], 1);
  sorted_se[pos] = int2{src, a0 | (a1 << 3) | (a2 << 6)};
}

// ---------------- graph boundaries from sorted batch: gs[g] = first node of graph g ----------------
__global__ __launch_bounds__(256) void k_gbounds(const int* __restrict__ batch,
                                                 int* __restrict__ gs) {
  int i = blockIdx.x * 256 + threadIdx.x;
  if (i >= N_NODES) return;
  int b = batch[i];
  int bp = (i == 0) ? -1 : batch[i - 1];
  for (int g = bp + 1; g <= b; ++g) gs[g] = i;
  if (i == N_NODES - 1) {
    for (int g = b + 1; g <= N_GRAPHS; ++g) gs[g] = N_NODES;
  }
}

// ---------------- W -> W_T bf16: wt[(layer*128+c)*384 + k], k = conv*128 + j ----------------
__global__ __launch_bounds__(384) void k_wconv(const float* __restrict__ W,
                                               unsigned short* __restrict__ wt) {
  int layer = blockIdx.x >> 7, c = blockIdx.x & 127, k = threadIdx.x;
  float v = W[(((layer * 3 + (k >> 7)) * 128) + (k & 127)) * 128 + c];
  wt[(size_t)blockIdx.x * 384 + k] = f2bf(v);
}

// ---------------- Fused layer: aggregate 16 nodes -> LDS tile -> MFMA GEMM + epilogue ----------------
// Round-13 structure (best) + NON-TEMPORAL hints on all streaming traffic:
// sorted_se loads (once/layer), h_in epilogue read, h_out store. h_bf stays
// NORMAL-cached (it is the 12.8 MB random-gather table; the ~64 MB/layer of
// streaming traffic was evicting it from L3, turning ~600cyc L3 gathers into
// ~900cyc HBM gathers — FETCH showed 76 MB vs 43 MB cold footprint).
// Phase 1: half-wave per node, 8-gather ILP, LDS combo (lgkmcnt-hidden),
// se-prefetch. Phase 2: wave wv owns cols wv*16..+15, resident B-frags,
// ds_read_b128 A, 12 chained MFMAs, inline bias+relu+residual. h ping-pong.
// VGPR ~52 (below the 64 occupancy boundary — round-12's 84 collapsed occ).
// A-frag: A[m=lane&15][k=(lane>>4)*8+j]; B-frag: B[k][n=lane&15];
// C/D: col=lane&15, row=(lane>>4)*4+reg.
__global__ __launch_bounds__(512) void k_layer(const int2* __restrict__ sorted_se,
                                               const int* __restrict__ row_start,
                                               const float* __restrict__ bl_bond,  // bond_emb[layer]: [3][8][3]
                                               const unsigned short* __restrict__ h_in_bf,
                                               const float* __restrict__ h_in,
                                               const unsigned short* __restrict__ wt,  // [128][384]
                                               const float* __restrict__ bl,  // [3][128]
                                               float* __restrict__ h_out,
                                               unsigned short* __restrict__ h_out_bf,
                                               int do_relu, int write_bf) {
  __shared__ float4 combo[512];                 // 8 KB
  __shared__ unsigned short ts[16 * TS_LD];     // 12.25 KB
  {
    int c = threadIdx.x;
    if (c < 512) {
      int a0i = c & 7, a1i = (c >> 3) & 7, a2i = (c >> 6) & 7;
      combo[c] = float4{
          bl_bond[a0i * 3 + 0] + bl_bond[24 + a1i * 3 + 0] + bl_bond[48 + a2i * 3 + 0],
          bl_bond[a0i * 3 + 1] + bl_bond[24 + a1i * 3 + 1] + bl_bond[48 + a2i * 3 + 1],
          bl_bond[a0i * 3 + 2] + bl_bond[24 + a1i * 3 + 2] + bl_bond[48 + a2i * 3 + 2], 0.f};
    }
  }
  __syncthreads();

  const int nb = blockIdx.x * 16;
  // ---- Phase 1: aggregate (se-prefetch pipeline, nt se loads) ----
  {
    const int hw = threadIdx.x >> 5;     // 0..15: node index in tile
    const int sub = threadIdx.x & 31;    // cols sub*4..+3
    const int node = nb + hw;
    const int beg = row_start[node], end = row_start[node + 1];
    float4 a0 = {0.f, 0.f, 0.f, 0.f}, a1 = a0, a2 = a0;
    if (beg < end) {
      int2 se_cur[8], se_nxt[8];
#pragma unroll
      for (int i = 0; i < 8; ++i) {
        int idx = beg + i;
        se_cur[i] = nt_se(&sorted_se[idx < end ? idx : end - 1]);
      }
      for (int e = beg; e < end; e += 8) {
        ushort4 u[8];
#pragma unroll
        for (int i = 0; i < 8; ++i)
          u[i] = *(const ushort4*)(h_in_bf + (size_t)se_cur[i].x * EMB + sub * 4);
        int e2 = e + 8;
        if (e2 < end) {
#pragma unroll
          for (int i = 0; i < 8; ++i) {
            int idx = e2 + i;
            se_nxt[i] = nt_se(&sorted_se[idx < end ? idx : end - 1]);
          }
        }
#pragma unroll
        for (int i = 0; i < 8; ++i) {
          float4 w = (e + i < end) ? combo[se_cur[i].y] : float4{0.f, 0.f, 0.f, 0.f};
          float v0 = bf2f(u[i].x), v1 = bf2f(u[i].y), v2 = bf2f(u[i].z), v3 = bf2f(u[i].w);
          a0.x += w.x * v0; a0.y += w.x * v1; a0.z += w.x * v2; a0.w += w.x * v3;
          a1.x += w.y * v0; a1.y += w.y * v1; a1.z += w.y * v2; a1.w += w.y * v3;
          a2.x += w.z * v0; a2.y += w.z * v1; a2.z += w.z * v2; a2.w += w.z * v3;
        }
#pragma unroll
        for (int i = 0; i < 8; ++i) se_cur[i] = se_nxt[i];
      }
    }
    unsigned short* tr = ts + hw * TS_LD + sub * 4;
    *(ushort4*)(tr)       = ushort4{f2bf(a0.x), f2bf(a0.y), f2bf(a0.z), f2bf(a0.w)};
    *(ushort4*)(tr + 128) = ushort4{f2bf(a1.x), f2bf(a1.y), f2bf(a1.z), f2bf(a1.w)};
    *(ushort4*)(tr + 256) = ushort4{f2bf(a2.x), f2bf(a2.y), f2bf(a2.z), f2bf(a2.w)};
  }
  __syncthreads();

  // ---- Phase 2: GEMM 16x384 @ 384x16 per wave ----
  const int wv = threadIdx.x >> 6;     // 0..7: column tile
  const int lane = threadIdx.x & 63;
  const int m = lane & 15;
  const int kq = lane >> 4;
  const int c = wv * 16 + m;

  const unsigned short* pB = wt + (size_t)c * TDIM + kq * 8;
  bf16x8 B[12];
#pragma unroll
  for (int kc = 0; kc < 12; ++kc) B[kc] = *(const bf16x8*)(pB + kc * 32);

  bf16x8 A[12];
  const unsigned short* pA = ts + m * TS_LD + kq * 8;
#pragma unroll
  for (int kc = 0; kc < 12; ++kc) A[kc] = *(const bf16x8*)(pA + kc * 32);

  f32x4 acc = {0.f, 0.f, 0.f, 0.f};
#pragma unroll
  for (int kc = 0; kc < 12; ++kc) acc = MFMA_BF16(A[kc], B[kc], acc);

  const float bias = bl[c] + bl[128 + c] + bl[256 + c];
#pragma unroll
  for (int r = 0; r < 4; ++r) {
    int row = nb + kq * 4 + r;
    size_t idx = (size_t)row * EMB + c;
    float v = acc[r] + bias;
    if (do_relu) v = fmaxf(v, 0.f);
    float hn = __builtin_nontemporal_load(&h_in[idx]) + v;
    __builtin_nontemporal_store(hn, &h_out[idx]);
    if (write_bf) h_out_bf[idx] = f2bf(hn);   // next layer's gather table: keep cached
  }
}

// ---------------- fused mean-pool + head: block g reduces its contiguous node range ----------------
__global__ __launch_bounds__(128) void k_head(const float* __restrict__ h,
                                              const int* __restrict__ gs,
                                              const float* __restrict__ fc1_w,
                                              const float* __restrict__ fc1_b,
                                              const float* __restrict__ fc2_w,
                                              const float* __restrict__ fc2_b,
                                              float* __restrict__ out) {
  __shared__ float hg[EMB];
  __shared__ float red[EMB];
  int g = blockIdx.x, e = threadIdx.x;
  int ns = gs[g], ne = gs[g + 1];
  float acc = 0.f;
  for (int n = ns; n < ne; ++n) acc += __builtin_nontemporal_load(&h[(size_t)n * EMB + e]);
  float cnt = fmaxf((float)(ne - ns), 1.f);
  hg[e] = acc / cnt;
  __syncthreads();
  float a2 = fc1_b[e];
  for (int j = 0; j < EMB; ++j) a2 += hg[j] * fc1_w[j * EMB + e];
  red[e] = a2 * fc2_w[e];
  __syncthreads();
  for (int s = 64; s > 0; s >>= 1) {
    if (e < s) red[e] += red[e + s];
    __syncthreads();
  }
  if (e == 0) out[g] = red[0] + fc2_b[0];
}

extern "C" void kernel_launch(void* const* d_in, const int* in_sizes, int n_in,
                              void* d_out, int out_size, void* d_ws, size_t ws_size,
                              hipStream_t stream) {
  const int*   x        = (const int*)d_in[0];
  const int*   ei       = (const int*)d_in[1];
  const int*   ea       = (const int*)d_in[2];
  const int*   batch    = (const int*)d_in[3];
  const float* atom_emb = (const float*)d_in[4];
  const float* bond_emb = (const float*)d_in[5];
  const float* W        = (const float*)d_in[6];
  const float* b        = (const float*)d_in[7];
  const float* fc1_w    = (const float*)d_in[8];
  const float* fc1_b    = (const float*)d_in[9];
  const float* fc2_w    = (const float*)d_in[10];
  const float* fc2_b    = (const float*)d_in[11];
  float* out = (float*)d_out;

  char* p = (char*)d_ws;
  auto alloc = [&](size_t bytes) { char* r = p; p += (bytes + 255) & ~(size_t)255; return r; };
  float*          h0         = (float*)alloc((size_t)HN * 4);
  float*          h1         = (float*)alloc((size_t)HN * 4);
  unsigned short* h0_bf      = (unsigned short*)alloc((size_t)HN * 2);
  unsigned short* h1_bf      = (unsigned short*)alloc((size_t)HN * 2);
  unsigned short* wt         = (unsigned short*)alloc((size_t)3 * 128 * TDIM * 2);
  int*            gs         = (int*)alloc((size_t)(N_GRAPHS + 1) * 4);
  int*            deg        = (int*)alloc((size_t)N_NODES * 4);
  int*            row_start  = (int*)alloc((size_t)(N_NODES + 1) * 4);
  int*            cursor     = (int*)alloc((size_t)N_NODES * 4);
  int*            partials   = (int*)alloc(256 * 4);
  int2*           sorted_se  = (int2*)alloc((size_t)(N_EDGES + 8) * 8);

  hipMemsetAsync(deg, 0, N_NODES * sizeof(int), stream);
  k_atom<<<N_NODES, 128, 0, stream>>>(x, atom_emb, h0, h0_bf);
  k_hist<<<(N_EDGES + 255) / 256, 256, 0, stream>>>(ei, deg);
  k_scan_a<<<SCAN_NB, 256, 0, stream>>>(deg, row_start, partials);
  k_scan_b<<<1, 256, 0, stream>>>(partials, row_start);
  k_scan_c<<<SCAN_NB, 256, 0, stream>>>(row_start, partials, cursor);
  k_scatter<<<(N_EDGES + 255) / 256, 256, 0, stream>>>(ei, ea, cursor, sorted_se);
  k_wconv<<<3 * 128, 384, 0, stream>>>(W, wt);
  k_gbounds<<<SCAN_NB, 256, 0, stream>>>(batch, gs);

  float* hi = h0;  unsigned short* hib = h0_bf;
  float* ho = h1;  unsigned short* hob = h1_bf;
  for (int layer = 0; layer < 3; ++layer) {
    k_layer<<<N_NODES / 16, 512, 0, stream>>>(
        sorted_se, row_start, bond_emb + layer * 72,
        hib, hi, wt + (size_t)layer * 128 * TDIM, b + layer * 3 * EMB,
        ho, hob, layer < 2 ? 1 : 0, layer < 2 ? 1 : 0);
    float* tf = hi; hi = ho; ho = tf;
    unsigned short* tb = hib; hib = hob; hob = tb;
  }
  // final h is in hi (h1 after 3 swaps)

  k_head<<<N_GRAPHS, 128, 0, stream>>>(hi, gs, fc1_w, fc1_b, fc2_w, fc2_b, out);
}

// Round 16
// 390.277 us; speedup vs baseline: 1.1576x; 1.1576x over previous
//
#include <hip/hip_runtime.h>

#define N_NODES 50000
#define N_EDGES 600000
#define N_GRAPHS 2048
#define EMB 128
#define TDIM 384
#define TS_LD 392               // padded LDS row stride (shorts): 2-way bank alias only
#define HN (N_NODES * EMB)
#define SCAN_NB ((N_NODES + 255) / 256)   // 196

typedef __attribute__((ext_vector_type(8))) short bf16x8;
typedef __attribute__((ext_vector_type(4))) float f32x4;
#define MFMA_BF16(a, b, c) __builtin_amdgcn_mfma_f32_16x16x32_bf16(a, b, c, 0, 0, 0)

__device__ inline unsigned short f2bf(float f) {
  unsigned int u = __float_as_uint(f);
  u += 0x7fffu + ((u >> 16) & 1u);   // round to nearest even
  return (unsigned short)(u >> 16);
}
__device__ inline float bf2f(unsigned short b) {
  return __uint_as_float(((unsigned int)b) << 16);
}

// ---------------- Atom encoder: h (fp32) + h_bf (bf16 shadow for gathers) ----------------
__global__ __launch_bounds__(128) void k_atom(const int* __restrict__ x,
                                              const float* __restrict__ atom_emb,
                                              float* __restrict__ h,
                                              unsigned short* __restrict__ h_bf) {
  int n = blockIdx.x, e = threadIdx.x;
  const int* xr = x + n * 9;
  float acc = 0.f;
#pragma unroll
  for (int c = 0; c < 9; ++c) acc += atom_emb[(c * 100 + xr[c]) * EMB + e];
  h[n * EMB + e] = acc;
  h_bf[n * EMB + e] = f2bf(acc);
}

// ---------------- CSR build ----------------
__global__ __launch_bounds__(256) void k_hist(const int* __restrict__ ei, int* __restrict__ deg) {
  int e = blockIdx.x * 256 + threadIdx.x;
  if (e < N_EDGES) atomicAdd(&deg[ei[N_EDGES + e]], 1);
}

__global__ __launch_bounds__(256) void k_scan_a(const int* __restrict__ deg,
                                                int* __restrict__ row_start,
                                                int* __restrict__ partials) {
  __shared__ int s[256];
  const int tid = threadIdx.x;
  const int i = blockIdx.x * 256 + tid;
  int v = (i < N_NODES) ? deg[i] : 0;
  s[tid] = v;
  __syncthreads();
  for (int off = 1; off < 256; off <<= 1) {
    int t = (tid >= off) ? s[tid - off] : 0;
    __syncthreads();
    s[tid] += t;
    __syncthreads();
  }
  if (i < N_NODES) row_start[i] = s[tid] - v;
  if (tid == 255) partials[blockIdx.x] = s[255];
}

__global__ __launch_bounds__(256) void k_scan_b(int* __restrict__ partials,
                                                int* __restrict__ row_start) {
  __shared__ int s[256];
  const int tid = threadIdx.x;
  int v = (tid < SCAN_NB) ? partials[tid] : 0;
  s[tid] = v;
  __syncthreads();
  for (int off = 1; off < 256; off <<= 1) {
    int t = (tid >= off) ? s[tid - off] : 0;
    __syncthreads();
    s[tid] += t;
    __syncthreads();
  }
  if (tid < SCAN_NB) partials[tid] = s[tid] - v;
  if (tid == 255) row_start[N_NODES] = s[255];
}

__global__ __launch_bounds__(256) void k_scan_c(int* __restrict__ row_start,
                                                const int* __restrict__ partials,
                                                int* __restrict__ cursor) {
  const int i = blockIdx.x * 256 + threadIdx.x;
  if (i < N_NODES) {
    int r = row_start[i] + partials[blockIdx.x];
    row_start[i] = r;
    cursor[i] = r;
  }
}

// Scatter edges into CSR order: one int2{src, packed_attr} per edge.
__global__ __launch_bounds__(256) void k_scatter(const int* __restrict__ ei,
                                                 const int* __restrict__ ea,
                                                 int* __restrict__ cursor,
                                                 int2* __restrict__ sorted_se) {
  int e = blockIdx.x * 256 + threadIdx.x;
  if (e >= N_EDGES) return;
  int src = ei[e], dst = ei[N_EDGES + e];
  int pos = atomicAdd(&cursor[dst], 1);
  int eap = ea[e * 3 + 0] | (ea[e * 3 + 1] << 3) | (ea[e * 3 + 2] << 6);
  sorted_se[pos] = int2{src, eap};
}

// ---------------- graph boundaries from sorted batch: gs[g] = first node of graph g ----------------
__global__ __launch_bounds__(256) void k_gbounds(const int* __restrict__ batch,
                                                 int* __restrict__ gs) {
  int i = blockIdx.x * 256 + threadIdx.x;
  if (i >= N_NODES) return;
  int b = batch[i];
  int bp = (i == 0) ? -1 : batch[i - 1];
  for (int g = bp + 1; g <= b; ++g) gs[g] = i;
  if (i == N_NODES - 1) {
    for (int g = b + 1; g <= N_GRAPHS; ++g) gs[g] = N_NODES;
  }
}

// ---------------- W -> W_T bf16: wt[(layer*128+c)*384 + k], k = conv*128 + j ----------------
__global__ __launch_bounds__(384) void k_wconv(const float* __restrict__ W,
                                               unsigned short* __restrict__ wt) {
  int layer = blockIdx.x >> 7, c = blockIdx.x & 127, k = threadIdx.x;
  float v = W[(((layer * 3 + (k >> 7)) * 128) + (k & 127)) * 128 + c];
  wt[(size_t)blockIdx.x * 384 + k] = f2bf(v);
}

// ---------------- Edge aggregation (round-9 form: 2 nodes/wave, ushort4, unroll-8) ----------------
// No barrier coupling, VGPR ~24, no big LDS -> high occupancy = many gathers in flight.
__global__ __launch_bounds__(256) void k_agg(const int2* __restrict__ sorted_se,
                                             const int* __restrict__ row_start,
                                             const float* __restrict__ bl,  // bond_emb[layer]: [3][8][3]
                                             const unsigned short* __restrict__ h_bf,
                                             unsigned short* __restrict__ t_bf) {
  __shared__ float4 combo[512];  // 8 KB
  for (int c = threadIdx.x; c < 512; c += 256) {
    int a0 = c & 7, a1 = (c >> 3) & 7, a2 = (c >> 6) & 7;
    combo[c] = float4{bl[a0 * 3 + 0] + bl[24 + a1 * 3 + 0] + bl[48 + a2 * 3 + 0],
                      bl[a0 * 3 + 1] + bl[24 + a1 * 3 + 1] + bl[48 + a2 * 3 + 1],
                      bl[a0 * 3 + 2] + bl[24 + a1 * 3 + 2] + bl[48 + a2 * 3 + 2], 0.f};
  }
  __syncthreads();
  const int node = blockIdx.x * 8 + (threadIdx.x >> 5);  // half-wave per node
  const int sub = threadIdx.x & 31;                      // cols sub*4..+3
  const int beg = row_start[node], end = row_start[node + 1];
  float4 a0 = {0.f, 0.f, 0.f, 0.f}, a1 = a0, a2 = a0;
  for (int e = beg; e < end; e += 8) {
    int2 se[8];
#pragma unroll
    for (int i = 0; i < 8; ++i) {
      int idx = e + i;
      se[i] = sorted_se[idx < end ? idx : end - 1];
    }
    ushort4 u[8];
#pragma unroll
    for (int i = 0; i < 8; ++i)
      u[i] = *(const ushort4*)(h_bf + (size_t)se[i].x * EMB + sub * 4);
#pragma unroll
    for (int i = 0; i < 8; ++i) {
      float4 w = (e + i < end) ? combo[se[i].y] : float4{0.f, 0.f, 0.f, 0.f};
      float v0 = bf2f(u[i].x), v1 = bf2f(u[i].y), v2 = bf2f(u[i].z), v3 = bf2f(u[i].w);
      a0.x += w.x * v0; a0.y += w.x * v1; a0.z += w.x * v2; a0.w += w.x * v3;
      a1.x += w.y * v0; a1.y += w.y * v1; a1.z += w.y * v2; a1.w += w.y * v3;
      a2.x += w.z * v0; a2.y += w.z * v1; a2.z += w.z * v2; a2.w += w.z * v3;
    }
  }
  size_t base = (size_t)node * TDIM + sub * 4;
  *(ushort4*)(t_bf + base)       = ushort4{f2bf(a0.x), f2bf(a0.y), f2bf(a0.z), f2bf(a0.w)};
  *(ushort4*)(t_bf + base + 128) = ushort4{f2bf(a1.x), f2bf(a1.y), f2bf(a1.z), f2bf(a1.w)};
  *(ushort4*)(t_bf + base + 256) = ushort4{f2bf(a2.x), f2bf(a2.y), f2bf(a2.z), f2bf(a2.w)};
}

// ---------------- MFMA GEMM: stage 32 t-rows into LDS (coalesced), then per-wave GEMM ----------------
// Block 512 thr = 8 waves; 32 nodes/block; grid 1563. Staging: sequential bf16x8
// loads of t_bf -> padded ts (no gather, no barrier tail). Wave wv owns cols
// wv*16..+15: 12 resident B-frags, 2 row-tiles (A via ds_read_b128), 12 chained
// MFMAs each, inline bias+relu+residual epilogue. h ping-pong (gather safety).
// A-frag: A[m=lane&15][k=(lane>>4)*8+j]; B-frag: B[k][n=lane&15];
// C/D: col=lane&15, row=(lane>>4)*4+reg.
__global__ __launch_bounds__(512) void k_gemm(const unsigned short* __restrict__ t_bf,
                                              const unsigned short* __restrict__ wt,  // [128][384]
                                              const float* __restrict__ bl,  // [3][128]
                                              const float* __restrict__ h_in,
                                              float* __restrict__ h_out,
                                              unsigned short* __restrict__ h_out_bf,
                                              int do_relu, int write_bf) {
  __shared__ unsigned short ts[32 * TS_LD];   // 24.5 KB
  const int nb = blockIdx.x * 32;
  // stage: 32 rows x 48 bf16x8 chunks
  for (int i = threadIdx.x; i < 32 * 48; i += 512) {
    int r = i / 48, cc = i % 48;
    bf16x8 v = {};
    int row = nb + r;
    if (row < N_NODES) v = *(const bf16x8*)(t_bf + (size_t)row * TDIM + cc * 8);
    *(bf16x8*)(ts + r * TS_LD + cc * 8) = v;
  }
  __syncthreads();

  const int wv = threadIdx.x >> 6;
  const int lane = threadIdx.x & 63;
  const int m = lane & 15;
  const int kq = lane >> 4;
  const int c = wv * 16 + m;

  const unsigned short* pB = wt + (size_t)c * TDIM + kq * 8;
  bf16x8 B[12];
#pragma unroll
  for (int kc = 0; kc < 12; ++kc) B[kc] = *(const bf16x8*)(pB + kc * 32);

  const float bias = bl[c] + bl[128 + c] + bl[256 + c];

#pragma unroll
  for (int rt = 0; rt < 2; ++rt) {
    const unsigned short* pA = ts + (rt * 16 + m) * TS_LD + kq * 8;
    bf16x8 A[12];
#pragma unroll
    for (int kc = 0; kc < 12; ++kc) A[kc] = *(const bf16x8*)(pA + kc * 32);
    f32x4 acc = {0.f, 0.f, 0.f, 0.f};
#pragma unroll
    for (int kc = 0; kc < 12; ++kc) acc = MFMA_BF16(A[kc], B[kc], acc);
#pragma unroll
    for (int r = 0; r < 4; ++r) {
      int row = nb + rt * 16 + kq * 4 + r;
      if (row < N_NODES) {
        size_t idx = (size_t)row * EMB + c;
        float v = acc[r] + bias;
        if (do_relu) v = fmaxf(v, 0.f);
        float hn = h_in[idx] + v;
        h_out[idx] = hn;
        if (write_bf) h_out_bf[idx] = f2bf(hn);
      }
    }
  }
}

// ---------------- fused mean-pool + head: block g reduces its contiguous node range ----------------
__global__ __launch_bounds__(128) void k_head(const float* __restrict__ h,
                                              const int* __restrict__ gs,
                                              const float* __restrict__ fc1_w,
                                              const float* __restrict__ fc1_b,
                                              const float* __restrict__ fc2_w,
                                              const float* __restrict__ fc2_b,
                                              float* __restrict__ out) {
  __shared__ float hg[EMB];
  __shared__ float red[EMB];
  int g = blockIdx.x, e = threadIdx.x;
  int ns = gs[g], ne = gs[g + 1];
  float acc = 0.f;
  for (int n = ns; n < ne; ++n) acc += h[(size_t)n * EMB + e];
  float cnt = fmaxf((float)(ne - ns), 1.f);
  hg[e] = acc / cnt;
  __syncthreads();
  float a2 = fc1_b[e];
  for (int j = 0; j < EMB; ++j) a2 += hg[j] * fc1_w[j * EMB + e];
  red[e] = a2 * fc2_w[e];
  __syncthreads();
  for (int s = 64; s > 0; s >>= 1) {
    if (e < s) red[e] += red[e + s];
    __syncthreads();
  }
  if (e == 0) out[g] = red[0] + fc2_b[0];
}

extern "C" void kernel_launch(void* const* d_in, const int* in_sizes, int n_in,
                              void* d_out, int out_size, void* d_ws, size_t ws_size,
                              hipStream_t stream) {
  const int*   x        = (const int*)d_in[0];
  const int*   ei       = (const int*)d_in[1];
  const int*   ea       = (const int*)d_in[2];
  const int*   batch    = (const int*)d_in[3];
  const float* atom_emb = (const float*)d_in[4];
  const float* bond_emb = (const float*)d_in[5];
  const float* W        = (const float*)d_in[6];
  const float* b        = (const float*)d_in[7];
  const float* fc1_w    = (const float*)d_in[8];
  const float* fc1_b    = (const float*)d_in[9];
  const float* fc2_w    = (const float*)d_in[10];
  const float* fc2_b    = (const float*)d_in[11];
  float* out = (float*)d_out;

  char* p = (char*)d_ws;
  auto alloc = [&](size_t bytes) { char* r = p; p += (bytes + 255) & ~(size_t)255; return r; };
  float*          h0         = (float*)alloc((size_t)HN * 4);
  float*          h1         = (float*)alloc((size_t)HN * 4);
  unsigned short* h0_bf      = (unsigned short*)alloc((size_t)HN * 2);
  unsigned short* h1_bf      = (unsigned short*)alloc((size_t)HN * 2);
  unsigned short* t_bf       = (unsigned short*)alloc((size_t)N_NODES * TDIM * 2);
  unsigned short* wt         = (unsigned short*)alloc((size_t)3 * 128 * TDIM * 2);
  int*            gs         = (int*)alloc((size_t)(N_GRAPHS + 1) * 4);
  int*            deg        = (int*)alloc((size_t)N_NODES * 4);
  int*            row_start  = (int*)alloc((size_t)(N_NODES + 1) * 4);
  int*            cursor     = (int*)alloc((size_t)N_NODES * 4);
  int*            partials   = (int*)alloc(256 * 4);
  int2*           sorted_se  = (int2*)alloc((size_t)(N_EDGES + 8) * 8);

  hipMemsetAsync(deg, 0, N_NODES * sizeof(int), stream);
  k_atom<<<N_NODES, 128, 0, stream>>>(x, atom_emb, h0, h0_bf);
  k_hist<<<(N_EDGES + 255) / 256, 256, 0, stream>>>(ei, deg);
  k_scan_a<<<SCAN_NB, 256, 0, stream>>>(deg, row_start, partials);
  k_scan_b<<<1, 256, 0, stream>>>(partials, row_start);
  k_scan_c<<<SCAN_NB, 256, 0, stream>>>(row_start, partials, cursor);
  k_scatter<<<(N_EDGES + 255) / 256, 256, 0, stream>>>(ei, ea, cursor, sorted_se);
  k_wconv<<<3 * 128, 384, 0, stream>>>(W, wt);
  k_gbounds<<<SCAN_NB, 256, 0, stream>>>(batch, gs);

  float* hi = h0;  unsigned short* hib = h0_bf;
  float* ho = h1;  unsigned short* hob = h1_bf;
  const int gemm_blocks = (N_NODES + 31) / 32;  // 1563
  for (int layer = 0; layer < 3; ++layer) {
    k_agg<<<N_NODES / 8, 256, 0, stream>>>(sorted_se, row_start, bond_emb + layer * 72,
                                           hib, t_bf);
    k_gemm<<<gemm_blocks, 512, 0, stream>>>(
        t_bf, wt + (size_t)layer * 128 * TDIM, b + layer * 3 * EMB,
        hi, ho, hob, layer < 2 ? 1 : 0, layer < 2 ? 1 : 0);
    float* tf = hi; hi = ho; ho = tf;
    unsigned short* tb = hib; hib = hob; hob = tb;
  }
  // final h is in hi (h1 after 3 swaps)

  k_head<<<N_GRAPHS, 128, 0, stream>>>(hi, gs, fc1_w, fc1_b, fc2_w, fc2_b, out);
}